// Round 10
// baseline (197.087 us; speedup 1.0000x reference)
//
#include <hip/hip_runtime.h>
#include <math.h>

// RechitsGCN fused — round 10: R9 base, serial-chain attack.
// 17->14 barriers (w1->P overlaps M6, w2->W overlaps LN-apply, parallel sN),
// all big outputs via coalesced tile_out overlapping next MFMA phase,
// adj clamps dropped, early weight loads.
#define Gg 1024
#define NT 1024

typedef __bf16 bf16x8 __attribute__((ext_vector_type(8)));
typedef float  f32x4  __attribute__((ext_vector_type(4)));

#define P_OFF   0
#define Q_OFF   32768
#define R_OFF   65536
#define W_OFF   98304
#define XB_OFF  131072
#define CO_OFF  141312
#define MS_OFF  142336
#define NK_OFF  142848
#define CS_OFF  143360
#define PL_OFF  145408
#define SN_OFF  149504
#define SMEM_SZ 149520

__device__ __forceinline__ unsigned short f2b(float f){
  return __builtin_bit_cast(unsigned short, (__bf16)f);
}
__device__ __forceinline__ float b2f(unsigned short h){
  return __uint_as_float(((unsigned)h) << 16);
}
__device__ __forceinline__ int SW(int row, int bc){ return (row << 8) + (bc ^ ((row & 7) << 4)); }

__device__ __forceinline__ void unp8(uint4 v, float* o){
  o[0]=b2f((unsigned short)(v.x&0xffffu)); o[1]=b2f((unsigned short)(v.x>>16));
  o[2]=b2f((unsigned short)(v.y&0xffffu)); o[3]=b2f((unsigned short)(v.y>>16));
  o[4]=b2f((unsigned short)(v.z&0xffffu)); o[5]=b2f((unsigned short)(v.z>>16));
  o[6]=b2f((unsigned short)(v.w&0xffffu)); o[7]=b2f((unsigned short)(v.w>>16));
}
__device__ __forceinline__ uint4 pk8(const float* f){
  uint4 v;
  v.x = (unsigned)f2b(f[0]) | ((unsigned)f2b(f[1])<<16);
  v.y = (unsigned)f2b(f[2]) | ((unsigned)f2b(f[3])<<16);
  v.z = (unsigned)f2b(f[4]) | ((unsigned)f2b(f[5])<<16);
  v.w = (unsigned)f2b(f[6]) | ((unsigned)f2b(f[7])<<16);
  return v;
}
__device__ __forceinline__ f32x4 MFMA(uint4 a, uint4 b, f32x4 c){
  return __builtin_amdgcn_mfma_f32_16x16x32_bf16(
      __builtin_bit_cast(bf16x8, a), __builtin_bit_cast(bf16x8, b), c, 0, 0, 0);
}
#define ZACC(A) { f32x4 z_={0.f,0.f,0.f,0.f}; A[0]=z_; A[1]=z_; A[2]=z_; A[3]=z_; }

__device__ __forceinline__ void mm_full(f32x4* acc, const char* A, const char* B,
                                        int p, int sub, int l15, int lhi){
  #pragma unroll
  for (int ks = 0; ks < 4; ks++){
    const int kb = ks*64 + lhi*16;
    const uint4 a = *(const uint4*)(A + SW(16*p + l15, kb));
    #pragma unroll
    for (int n0 = 0; n0 < 4; n0++){
      const uint4 b = *(const uint4*)(B + SW((sub*4 + n0)*16 + l15, kb));
      acc[n0] = MFMA(a, b, acc[n0]);
    }
  }
}
__device__ __forceinline__ void mmX(f32x4* acc, const char* Xb, const char* Wt,
                                    int p, int sub, int l15, int lhi){
  const uint4 a = *(const uint4*)(Xb + 80*(16*p + l15) + lhi*16);
  #pragma unroll
  for (int n0 = 0; n0 < 4; n0++){
    const uint4 b = *(const uint4*)(Wt + 80*((sub*4 + n0)*16 + l15) + lhi*16);
    acc[n0] = MFMA(a, b, acc[n0]);
  }
}
__device__ __forceinline__ void frag_store(char* buf, const f32x4* acc,
                                           int p, int sub, int l15, int lhi){
  #pragma unroll
  for (int n0 = 0; n0 < 4; n0++){
    const int col = (sub*4 + n0)*16 + l15;
    #pragma unroll
    for (int q = 0; q < 4; q++)
      *(unsigned short*)(buf + SW(16*p + 4*lhi + q, 2*col)) = f2b(acc[n0][q]);
  }
}
__device__ __forceinline__ void fragT_store(char* buf, const f32x4* acc,
                                            int p, int sub, int l15, int lhi){
  const int row0 = 16*p + 4*lhi;
  #pragma unroll
  for (int n0 = 0; n0 < 4; n0++){
    const int col = (sub*4 + n0)*16 + l15;
    uint2 u;
    u.x = (unsigned)f2b(acc[n0][0]) | ((unsigned)f2b(acc[n0][1])<<16);
    u.y = (unsigned)f2b(acc[n0][2]) | ((unsigned)f2b(acc[n0][3])<<16);
    *(uint2*)(buf + SW(col, 2*row0)) = u;
  }
}
// LDS bf16 tile -> global f32, 512-B row segments per 16-lane group
__device__ __forceinline__ void tile_out(const char* buf, float* dst, int tid){
  #pragma unroll
  for (int c = 0; c < 2; c++){
    const int chunk = c*NT + tid;
    const int r = chunk >> 4, slot = chunk & 15;
    uint4 v = *(const uint4*)(buf + SW(r, slot*16));
    float o[8]; unp8(v, o);
    *(float4*)(dst + (size_t)r*128 + slot*8)     = make_float4(o[0],o[1],o[2],o[3]);
    *(float4*)(dst + (size_t)r*128 + slot*8 + 4) = make_float4(o[4],o[5],o[6],o[7]);
  }
}
__device__ __forceinline__ void stageW(char* W, const unsigned short* src, int tid){
  #pragma unroll
  for (int q = 0; q < 2; q++){
    const int chunk = q*NT + tid;
    const uint4 v = *(const uint4*)(src + chunk*8);
    *(uint4*)(W + SW(chunk >> 4, (chunk & 15)*16)) = v;
  }
}
__device__ __forceinline__ void loadW(uint4* r, const unsigned short* src, int tid){
  r[0] = *(const uint4*)(src + (size_t)tid*8);
  r[1] = *(const uint4*)(src + (size_t)(NT + tid)*8);
}
__device__ __forceinline__ void writeW(char* W, const uint4* r, int tid){
  *(uint4*)(W + SW(tid >> 4, (tid & 15)*16)) = r[0];
  *(uint4*)(W + SW((NT + tid) >> 4, ((NT + tid) & 15)*16)) = r[1];
}

__global__ __launch_bounds__(128) void prep_wqkT(const float* __restrict__ wq,
                                                 const float* __restrict__ wk,
                                                 unsigned short* __restrict__ ws16){
  __shared__ unsigned short wqb[128*130];
  __shared__ float wkr[128];
  const int h = blockIdx.x, t = threadIdx.x;
  for (int i = t; i < 16384; i += 128){ int a = i >> 7, c = i & 127; wqb[a*130+c] = f2b(wq[i]); }
  wkr[t] = wk[h*128 + t];
  __syncthreads();
  float s = 0.f;
  for (int c = 0; c < 128; c++) s += b2f(wqb[t*130 + c]) * wkr[c];
  ws16[h*128 + t] = f2b(s * 0.08838834764831845f);
}

__global__ __launch_bounds__(256) void prep_T(const float* __restrict__ wv,
                                              const float* __restrict__ w1,
                                              const float* __restrict__ w2,
                                              const float* __restrict__ theta,
                                              const float* __restrict__ w_t,
                                              unsigned short* __restrict__ ws16){
  const int i = blockIdx.x*256 + threadIdx.x;
  if (i < 49152){
    const int which = i >> 14, r = i & 16383;
    const int hh = r >> 7, aa = r & 127;
    const float* s = (which == 0) ? wv : (which == 1) ? w1 : w2;
    ws16[16384 + i] = f2b(s[aa*128 + hh]);
  } else if (i < 57344){
    const int t2 = i - 49152;
    const int mat = t2 >> 12, r = t2 & 4095;
    const int hh = r >> 5, kk = r & 31;
    const float* s = (mat == 0) ? theta : w_t;
    ws16[16384 + i] = (kk < 18) ? f2b(s[kk*128 + hh]) : (unsigned short)0;
  }
}

__global__ void __launch_bounds__(NT)
__attribute__((amdgpu_waves_per_eu(4, 4)))
fused_gcn(const float* __restrict__ x, const float* __restrict__ mask,
          const float* __restrict__ b_t, const unsigned short* __restrict__ ws16,
          const float* __restrict__ b1, const float* __restrict__ b2,
          const float* __restrict__ g_sa, const float* __restrict__ be_sa,
          const float* __restrict__ g_out, const float* __restrict__ be_out,
          float* __restrict__ out)
{
  extern __shared__ char smc[];
  char* Pb = smc + P_OFF;
  char* Qb = smc + Q_OFF;
  char* Rb = smc + R_OFF;
  char* Wb = smc + W_OFF;
  char* Xb = smc + XB_OFF;
  float* coords = (float*)(smc + CO_OFF);
  float* msh    = (float*)(smc + MS_OFF);
  float* nk     = (float*)(smc + NK_OFF);
  float* csum   = (float*)(smc + CS_OFF);
  float* pool   = (float*)(smc + PL_OFF);
  float* sN     = (float*)(smc + SN_OFF);

  const int g    = blockIdx.x;
  const int tid  = threadIdx.x;
  const int lane = tid & 63;
  const int wv_  = tid >> 6;
  const int p    = wv_ >> 1;
  const int sub  = wv_ & 1;
  const int l15  = lane & 15;
  const int lhi  = lane >> 4;
  const int rt2  = tid >> 4;
  const int ct   = tid & 15;

  const size_t gRH = (size_t)g * 16384;
  float* out0  = out;
  float* sa_o  = out + (size_t)Gg*128 + gRH;
  float* den_o = out + (size_t)Gg*128 + (size_t)Gg*16384 + gRH;
  float* att_o = out + (size_t)Gg*128 + 2*(size_t)Gg*16384 + gRH;
  float* adj_o = out + (size_t)Gg*128 + 3*(size_t)Gg*16384 + gRH;

  // ---- S0: stage x->Xb bf16, coords, mask, thetaT/w_tT->W ----
  {
    const float* xg = x + (size_t)g * 2304;
    for (int i = tid; i < 2304; i += NT){
      const int r = i / 18, k = i - r*18;
      *(unsigned short*)(Xb + r*80 + k*2) = f2b(xg[i]);
    }
    if (tid < 128){
      #pragma unroll
      for (int c = 18; c < 32; c += 2) *(unsigned*)(Xb + tid*80 + c*2) = 0u;
      msh[tid] = mask[(size_t)g*128 + tid];
    }
    if (tid < 256) coords[tid] = xg[(tid >> 1)*18 + (tid & 1)];
    {
      const int which = tid >> 9, t = tid & 511;
      const uint4 v = *(const uint4*)(ws16 + 65536 + which*4096 + t*8);
      *(uint4*)(Wb + which*10240 + (t >> 2)*80 + (t & 3)*16) = v;
    }
  }
  __syncthreads();                                       // B0
  if (tid < 64){                                         // parallel sN (wave 0)
    float v = msh[tid] + msh[tid + 64];
    #pragma unroll
    for (int o = 1; o < 64; o <<= 1) v += __shfl_xor(v, o);
    if (tid == 0) *sN = v;
  }

  // ---- S3 (MFMA): f_het, gate; f_hetT -> Q ----
  f32x4 fhet[4]; float gate[4][4];
  {
    f32x4 gf[4];
    ZACC(fhet); ZACC(gf);
    mmX(fhet, Xb, Wb, p, sub, l15, lhi);
    mmX(gf,   Xb, Wb + 10240, p, sub, l15, lhi);
    #pragma unroll
    for (int n0 = 0; n0 < 4; n0++){
      const float btv = b_t[(sub*4 + n0)*16 + l15];
      #pragma unroll
      for (int q = 0; q < 4; q++)
        gate[n0][q] = 1.f / (1.f + __expf(-(gf[n0][q] + btv)));
    }
    fragT_store(Qb, fhet, p, sub, l15, lhi);
  }

  // ---- S1: adj (no clamps: |diff| <= 1e-6 << 0.089 threshold) -> adj_o + regs; nk ----
  float av[2][8];
  {
    float sc0[8], sc1[8], smv[8];
    #pragma unroll
    for (int j = 0; j < 8; j++){
      const int s = 8*ct + j;
      sc0[j] = coords[2*s]; sc1[j] = coords[2*s + 1]; smv[j] = msh[s];
    }
    #pragma unroll
    for (int i = 0; i < 2; i++){
      const int r = 2*rt2 + i;
      const float c0 = coords[2*r], c1 = coords[2*r + 1];
      const float mr = msh[r];
      float dsum = 0.f;
      #pragma unroll
      for (int j = 0; j < 8; j++){
        const float dx = c0 - sc0[j], dy = c1 - sc1[j];
        const float dsq = dx*dx + dy*dy;
        const float a = __expf(-__fsqrt_rn(dsq)) * (mr * smv[j]);
        av[i][j] = a; dsum += a;
      }
      #pragma unroll
      for (int o = 1; o < 16; o <<= 1) dsum += __shfl_xor(dsum, o);
      if (ct == 0){ const float t = dsum + 1e-6f; const float rs = __frsqrt_rn(t); nk[r] = rs*rs*rs; }
      *(float4*)(adj_o + (size_t)r*128 + 8*ct)     = make_float4(av[i][0],av[i][1],av[i][2],av[i][3]);
      *(float4*)(adj_o + (size_t)r*128 + 8*ct + 4) = make_float4(av[i][4],av[i][5],av[i][6],av[i][7]);
    }
  }
  __syncthreads();                                       // B1

  // ---- S2: A' = adj^3 * nk[r]*nk[s] -> P ----
  {
    float nkc[8];
    #pragma unroll
    for (int j = 0; j < 8; j++) nkc[j] = nk[8*ct + j];
    #pragma unroll
    for (int i = 0; i < 2; i++){
      const int r = 2*rt2 + i;
      const float nr = nk[r];
      float tv[8];
      #pragma unroll
      for (int j = 0; j < 8; j++){ const float a = av[i][j]; tv[j] = a*a*a*nr*nkc[j]; }
      *(uint4*)(Pb + SW(r, 16*ct)) = pk8(tv);
    }
  }
  __syncthreads();                                       // B2

  stageW(Wb, ws16, tid);                                 // wqkT (overlaps M2)

  // ---- M2: f_hom_pre = A' @ f_het ----
  f32x4 acc[4];
  ZACC(acc);
  mm_full(acc, Pb, Qb, p, sub, l15, lhi);
  __syncthreads();                                       // B4

  // ---- S5: og -> R + ogT -> Q ----
  {
    f32x4 ogv[4];
    #pragma unroll
    for (int n0 = 0; n0 < 4; n0++)
      #pragma unroll
      for (int q = 0; q < 4; q++){
        const float gv = gate[n0][q];
        ogv[n0][q] = gv * fmaxf(acc[n0][q], 0.f) + (1.f - gv) * fhet[n0][q];
      }
    frag_store(Rb, ogv, p, sub, l15, lhi);
    fragT_store(Qb, ogv, p, sub, l15, lhi);
  }
  __syncthreads();                                       // B5

  // ---- M3: t = og @ wqk -> P ----
  ZACC(acc);
  mm_full(acc, Rb, Wb, p, sub, l15, lhi);
  frag_store(Pb, acc, p, sub, l15, lhi);
  __syncthreads();                                       // B6

  stageW(Wb, ws16 + 16384, tid);                         // wvT (overlaps M4)
  uint4 w1r[2];
  loadW(w1r, ws16 + 32768, tid);                         // w1T in flight early

  // ---- M4: logits; no-max masked softmax ----
  ZACC(acc);
  mm_full(acc, Pb, Rb, p, sub, l15, lhi);
  float ee[4][4];
  {
    float msv[4];
    #pragma unroll
    for (int n0 = 0; n0 < 4; n0++) msv[n0] = msh[(sub*4 + n0)*16 + l15];
    #pragma unroll
    for (int q = 0; q < 4; q++){
      const int row = 16*p + 4*lhi + q;
      float se = 0.f;
      #pragma unroll
      for (int n0 = 0; n0 < 4; n0++){
        const float e = __expf(acc[n0][q]) * msv[n0];
        ee[n0][q] = e; se += e;
      }
      #pragma unroll
      for (int o = 1; o < 16; o <<= 1) se += __shfl_xor(se, o);
      if (l15 == 0) csum[row*2 + sub] = se;
    }
  }
  __syncthreads();                                       // B7
  #pragma unroll
  for (int q = 0; q < 4; q++){
    const int row = 16*p + 4*lhi + q;
    const float inv = 1.f / (csum[row*2] + csum[row*2 + 1]);
    #pragma unroll
    for (int n0 = 0; n0 < 4; n0++)
      *(unsigned short*)(Pb + SW(row, 2*((sub*4 + n0)*16 + l15))) = f2b(ee[n0][q] * inv);
  }
  __syncthreads();                                       // B8 (attn tile in P)

  // ---- M5: u = attn @ og -> R ; attn -> global (coalesced, overlaps M5) ----
  ZACC(acc);
  mm_full(acc, Pb, Qb, p, sub, l15, lhi);
  tile_out(Pb, att_o, tid);
  uint4 w2r[2];
  loadW(w2r, ws16 + 49152, tid);                         // w2T in flight
  frag_store(Rb, acc, p, sub, l15, lhi);
  __syncthreads();                                       // B9 (P free, Q free)

  writeW(Pb, w1r, tid);                                  // w1T -> P (overlaps M6)

  // ---- M6: sa_pre = u @ wv ; LN-sum ----
  ZACC(acc);
  mm_full(acc, Rb, Wb, p, sub, l15, lhi);
  {
    #pragma unroll
    for (int q = 0; q < 4; q++){
      const int row = 16*p + 4*lhi + q;
      float s1 = 0.f, s2 = 0.f;
      #pragma unroll
      for (int n0 = 0; n0 < 4; n0++){ const float v = acc[n0][q]; s1 += v; s2 += v*v; }
      #pragma unroll
      for (int o = 1; o < 16; o <<= 1){ s1 += __shfl_xor(s1, o); s2 += __shfl_xor(s2, o); }
      if (l15 == 0){ csum[row*4 + sub*2] = s1; csum[row*4 + sub*2 + 1] = s2; }
    }
  }
  __syncthreads();                                       // B10 (W reads done)

  writeW(Wb, w2r, tid);                                  // w2T -> W (overlaps LN-apply)

  // ---- LN-apply: sa -> Q + sav regs ----
  f32x4 sav[4];
  {
    float gsa[4], bsa[4];
    #pragma unroll
    for (int n0 = 0; n0 < 4; n0++){ const int c = (sub*4+n0)*16 + l15; gsa[n0] = g_sa[c]; bsa[n0] = be_sa[c]; }
    #pragma unroll
    for (int q = 0; q < 4; q++){
      const int row = 16*p + 4*lhi + q;
      const float s1 = csum[row*4] + csum[row*4 + 2];
      const float s2 = csum[row*4 + 1] + csum[row*4 + 3];
      const float mean = s1 * 0.0078125f;
      const float var  = s2 * 0.0078125f - mean*mean;
      const float rstd = __frsqrt_rn(var + 1e-3f);
      const float mr = msh[row];
      #pragma unroll
      for (int n0 = 0; n0 < 4; n0++)
        sav[n0][q] = ((acc[n0][q] - mean) * rstd * gsa[n0] + bsa[n0]) * mr;
    }
    frag_store(Qb, sav, p, sub, l15, lhi);
  }
  __syncthreads();                                       // B11 (sa in Q; w1 in P; w2 in W)

  // ---- M7: d1 = relu(sa @ w1 + b1) -> R ; sa -> global (overlaps M7) ----
  ZACC(acc);
  mm_full(acc, Qb, Pb, p, sub, l15, lhi);
  tile_out(Qb, sa_o, tid);
  {
    f32x4 d1v[4];
    #pragma unroll
    for (int n0 = 0; n0 < 4; n0++){
      const float b1v = b1[(sub*4 + n0)*16 + l15];
      #pragma unroll
      for (int q = 0; q < 4; q++) d1v[n0][q] = fmaxf(acc[n0][q] + b1v, 0.f);
    }
    frag_store(Rb, d1v, p, sub, l15, lhi);
  }
  __syncthreads();                                       // B12

  // ---- M8: d2 = relu(d1@w2+b2); dense-sum ----
  ZACC(acc);
  mm_full(acc, Rb, Wb, p, sub, l15, lhi);
  float dd[4][4];
  {
    float b2v[4];
    #pragma unroll
    for (int n0 = 0; n0 < 4; n0++) b2v[n0] = b2[(sub*4 + n0)*16 + l15];
    #pragma unroll
    for (int q = 0; q < 4; q++){
      const int row = 16*p + 4*lhi + q;
      float s1 = 0.f, s2 = 0.f;
      #pragma unroll
      for (int n0 = 0; n0 < 4; n0++){
        const float v = fmaxf(acc[n0][q] + b2v[n0], 0.f) + sav[n0][q];
        dd[n0][q] = v; s1 += v; s2 += v*v;
      }
      #pragma unroll
      for (int o = 1; o < 16; o <<= 1){ s1 += __shfl_xor(s1, o); s2 += __shfl_xor(s2, o); }
      if (l15 == 0){ csum[row*4 + sub*2] = s1; csum[row*4 + sub*2 + 1] = s2; }
    }
  }
  __syncthreads();                                       // B13 (P w1-reads done)

  // ---- LN-apply dense -> P ; pool partials ----
  {
    float gov[4], bov[4], cs[4] = {0.f,0.f,0.f,0.f};
    #pragma unroll
    for (int n0 = 0; n0 < 4; n0++){ const int c = (sub*4+n0)*16 + l15; gov[n0] = g_out[c]; bov[n0] = be_out[c]; }
    f32x4 dnv[4];
    #pragma unroll
    for (int q = 0; q < 4; q++){
      const int row = 16*p + 4*lhi + q;
      const float s1 = csum[row*4] + csum[row*4 + 2];
      const float s2 = csum[row*4 + 1] + csum[row*4 + 3];
      const float mean = s1 * 0.0078125f;
      const float var  = s2 * 0.0078125f - mean*mean;
      const float rstd = __frsqrt_rn(var + 1e-3f);
      const float mr = msh[row];
      #pragma unroll
      for (int n0 = 0; n0 < 4; n0++){
        const float y = ((dd[n0][q] - mean) * rstd * gov[n0] + bov[n0]) * mr;
        dnv[n0][q] = y;
        cs[n0] += y;
      }
    }
    frag_store(Pb, dnv, p, sub, l15, lhi);
    #pragma unroll
    for (int n0 = 0; n0 < 4; n0++){
      float v = cs[n0];
      v += __shfl_xor(v, 16); v += __shfl_xor(v, 32);
      if (lhi == 0) pool[p*128 + (sub*4 + n0)*16 + l15] = v;
    }
  }
  __syncthreads();                                       // B14 (last)

  tile_out(Pb, den_o, tid);                              // dense -> global
  if (tid < 128){
    float s = 0.f;
    #pragma unroll
    for (int q = 0; q < 8; q++) s += pool[q*128 + tid];
    const float n = *sN;
    out0[(size_t)g*128 + tid] = (n > 0.f) ? (s / n) : 0.f;
  }
}

extern "C" void kernel_launch(void* const* d_in, const int* in_sizes, int n_in,
                              void* d_out, int out_size, void* d_ws, size_t ws_size,
                              hipStream_t stream) {
  (void)in_sizes; (void)n_in; (void)out_size; (void)ws_size;
  const float* x     = (const float*)d_in[0];
  const float* mask  = (const float*)d_in[1];
  const float* theta = (const float*)d_in[2];
  const float* w_t   = (const float*)d_in[3];
  const float* b_t   = (const float*)d_in[4];
  const float* wq    = (const float*)d_in[5];
  const float* wk    = (const float*)d_in[6];
  const float* wvp   = (const float*)d_in[7];
  const float* w1    = (const float*)d_in[8];
  const float* b1    = (const float*)d_in[9];
  const float* w2    = (const float*)d_in[10];
  const float* b2    = (const float*)d_in[11];
  const float* g_sa  = (const float*)d_in[12];
  const float* be_sa = (const float*)d_in[13];
  const float* g_out = (const float*)d_in[14];
  const float* be_out= (const float*)d_in[15];
  unsigned short* ws16 = (unsigned short*)d_ws;

  prep_wqkT<<<dim3(128), dim3(128), 0, stream>>>(wq, wk, ws16);
  prep_T<<<dim3(224), dim3(256), 0, stream>>>(wvp, w1, w2, theta, w_t, ws16);

  (void)hipFuncSetAttribute(reinterpret_cast<const void*>(fused_gcn),
                            hipFuncAttributeMaxDynamicSharedMemorySize, SMEM_SZ);
  fused_gcn<<<dim3(Gg), dim3(NT), SMEM_SZ, stream>>>(
      x, mask, b_t, ws16, b1, b2, g_sa, be_sa, g_out, be_out, (float*)d_out);
}

// Round 11
// 180.081 us; speedup vs baseline: 1.0944x; 1.0944x over previous
//
#include <hip/hip_runtime.h>
#include <math.h>

// RechitsGCN fused — round 11: R9 base + live-register reduction.
// fhet and sav no longer held across MFMA phases (LDS round-trips through
// tiles that are free anyway) -> fits the 64-VGPR allocation, kills spills.
#define Gg 1024
#define NT 1024

typedef __bf16 bf16x8 __attribute__((ext_vector_type(8)));
typedef float  f32x4  __attribute__((ext_vector_type(4)));

#define P_OFF   0
#define Q_OFF   32768
#define R_OFF   65536
#define W_OFF   98304
#define XB_OFF  131072
#define CO_OFF  141312
#define MS_OFF  142336
#define NK_OFF  142848
#define CS_OFF  143360
#define PL_OFF  145408
#define SN_OFF  149504
#define SMEM_SZ 149520

__device__ __forceinline__ unsigned short f2b(float f){
  return __builtin_bit_cast(unsigned short, (__bf16)f);
}
__device__ __forceinline__ float b2f(unsigned short h){
  return __uint_as_float(((unsigned)h) << 16);
}
__device__ __forceinline__ int SW(int row, int bc){ return (row << 8) + (bc ^ ((row & 7) << 4)); }

__device__ __forceinline__ uint4 pk8(const float* f){
  uint4 v;
  v.x = (unsigned)f2b(f[0]) | ((unsigned)f2b(f[1])<<16);
  v.y = (unsigned)f2b(f[2]) | ((unsigned)f2b(f[3])<<16);
  v.z = (unsigned)f2b(f[4]) | ((unsigned)f2b(f[5])<<16);
  v.w = (unsigned)f2b(f[6]) | ((unsigned)f2b(f[7])<<16);
  return v;
}
__device__ __forceinline__ f32x4 MFMA(uint4 a, uint4 b, f32x4 c){
  return __builtin_amdgcn_mfma_f32_16x16x32_bf16(
      __builtin_bit_cast(bf16x8, a), __builtin_bit_cast(bf16x8, b), c, 0, 0, 0);
}
#define ZACC(A) { f32x4 z_={0.f,0.f,0.f,0.f}; A[0]=z_; A[1]=z_; A[2]=z_; A[3]=z_; }

__device__ __forceinline__ void mm_full(f32x4* acc, const char* A, const char* B,
                                        int p, int sub, int l15, int lhi){
  #pragma unroll
  for (int ks = 0; ks < 4; ks++){
    const int kb = ks*64 + lhi*16;
    const uint4 a = *(const uint4*)(A + SW(16*p + l15, kb));
    #pragma unroll
    for (int n0 = 0; n0 < 4; n0++){
      const uint4 b = *(const uint4*)(B + SW((sub*4 + n0)*16 + l15, kb));
      acc[n0] = MFMA(a, b, acc[n0]);
    }
  }
}
__device__ __forceinline__ void mmX(f32x4* acc, const char* Xb, const char* Wt,
                                    int p, int sub, int l15, int lhi){
  const uint4 a = *(const uint4*)(Xb + 80*(16*p + l15) + lhi*16);
  #pragma unroll
  for (int n0 = 0; n0 < 4; n0++){
    const uint4 b = *(const uint4*)(Wt + 80*((sub*4 + n0)*16 + l15) + lhi*16);
    acc[n0] = MFMA(a, b, acc[n0]);
  }
}
__device__ __forceinline__ void frag_store(char* buf, const f32x4* acc,
                                           int p, int sub, int l15, int lhi){
  #pragma unroll
  for (int n0 = 0; n0 < 4; n0++){
    const int col = (sub*4 + n0)*16 + l15;
    #pragma unroll
    for (int q = 0; q < 4; q++)
      *(unsigned short*)(buf + SW(16*p + 4*lhi + q, 2*col)) = f2b(acc[n0][q]);
  }
}
__device__ __forceinline__ void fragT_store(char* buf, const f32x4* acc,
                                            int p, int sub, int l15, int lhi){
  const int row0 = 16*p + 4*lhi;
  #pragma unroll
  for (int n0 = 0; n0 < 4; n0++){
    const int col = (sub*4 + n0)*16 + l15;
    uint2 u;
    u.x = (unsigned)f2b(acc[n0][0]) | ((unsigned)f2b(acc[n0][1])<<16);
    u.y = (unsigned)f2b(acc[n0][2]) | ((unsigned)f2b(acc[n0][3])<<16);
    *(uint2*)(buf + SW(col, 2*row0)) = u;
  }
}
__device__ __forceinline__ void stageW(char* W, const unsigned short* src, int tid){
  #pragma unroll
  for (int q = 0; q < 2; q++){
    const int chunk = q*NT + tid;
    const uint4 v = *(const uint4*)(src + chunk*8);
    *(uint4*)(W + SW(chunk >> 4, (chunk & 15)*16)) = v;
  }
}
__device__ __forceinline__ void loadW(uint4* r, const unsigned short* src, int tid){
  r[0] = *(const uint4*)(src + (size_t)tid*8);
  r[1] = *(const uint4*)(src + (size_t)(NT + tid)*8);
}
__device__ __forceinline__ void writeW(char* W, const uint4* r, int tid){
  *(uint4*)(W + SW(tid >> 4, (tid & 15)*16)) = r[0];
  *(uint4*)(W + SW((NT + tid) >> 4, ((NT + tid) & 15)*16)) = r[1];
}

__global__ __launch_bounds__(128) void prep_wqkT(const float* __restrict__ wq,
                                                 const float* __restrict__ wk,
                                                 unsigned short* __restrict__ ws16){
  __shared__ unsigned short wqb[128*130];
  __shared__ float wkr[128];
  const int h = blockIdx.x, t = threadIdx.x;
  for (int i = t; i < 16384; i += 128){ int a = i >> 7, c = i & 127; wqb[a*130+c] = f2b(wq[i]); }
  wkr[t] = wk[h*128 + t];
  __syncthreads();
  float s = 0.f;
  for (int c = 0; c < 128; c++) s += b2f(wqb[t*130 + c]) * wkr[c];
  ws16[h*128 + t] = f2b(s * 0.08838834764831845f);
}

__global__ __launch_bounds__(256) void prep_T(const float* __restrict__ wv,
                                              const float* __restrict__ w1,
                                              const float* __restrict__ w2,
                                              const float* __restrict__ theta,
                                              const float* __restrict__ w_t,
                                              unsigned short* __restrict__ ws16){
  const int i = blockIdx.x*256 + threadIdx.x;
  if (i < 49152){
    const int which = i >> 14, r = i & 16383;
    const int hh = r >> 7, aa = r & 127;
    const float* s = (which == 0) ? wv : (which == 1) ? w1 : w2;
    ws16[16384 + i] = f2b(s[aa*128 + hh]);
  } else if (i < 57344){
    const int t2 = i - 49152;
    const int mat = t2 >> 12, r = t2 & 4095;
    const int hh = r >> 5, kk = r & 31;
    const float* s = (mat == 0) ? theta : w_t;
    ws16[16384 + i] = (kk < 18) ? f2b(s[kk*128 + hh]) : (unsigned short)0;
  }
}

__global__ void __launch_bounds__(NT)
__attribute__((amdgpu_waves_per_eu(4, 4)))
fused_gcn(const float* __restrict__ x, const float* __restrict__ mask,
          const float* __restrict__ b_t, const unsigned short* __restrict__ ws16,
          const float* __restrict__ b1, const float* __restrict__ b2,
          const float* __restrict__ g_sa, const float* __restrict__ be_sa,
          const float* __restrict__ g_out, const float* __restrict__ be_out,
          float* __restrict__ out)
{
  extern __shared__ char smc[];
  char* Pb = smc + P_OFF;
  char* Qb = smc + Q_OFF;
  char* Rb = smc + R_OFF;
  char* Wb = smc + W_OFF;
  char* Xb = smc + XB_OFF;
  float* coords = (float*)(smc + CO_OFF);
  float* msh    = (float*)(smc + MS_OFF);
  float* nk     = (float*)(smc + NK_OFF);
  float* csum   = (float*)(smc + CS_OFF);
  float* pool   = (float*)(smc + PL_OFF);
  float* sN     = (float*)(smc + SN_OFF);

  const int g    = blockIdx.x;
  const int tid  = threadIdx.x;
  const int lane = tid & 63;
  const int wv_  = tid >> 6;
  const int p    = wv_ >> 1;
  const int sub  = wv_ & 1;
  const int l15  = lane & 15;
  const int lhi  = lane >> 4;
  const int rt2  = tid >> 4;
  const int ct   = tid & 15;

  const size_t gRH = (size_t)g * 16384;
  float* out0  = out;
  float* sa_o  = out + (size_t)Gg*128 + gRH;
  float* den_o = out + (size_t)Gg*128 + (size_t)Gg*16384 + gRH;
  float* att_o = out + (size_t)Gg*128 + 2*(size_t)Gg*16384 + gRH;
  float* adj_o = out + (size_t)Gg*128 + 3*(size_t)Gg*16384 + gRH;

  // ---- S0: stage x->Xb bf16, coords, mask, thetaT/w_tT->W ----
  {
    const float* xg = x + (size_t)g * 2304;
    for (int i = tid; i < 2304; i += NT){
      const int r = i / 18, k = i - r*18;
      *(unsigned short*)(Xb + r*80 + k*2) = f2b(xg[i]);
    }
    if (tid < 128){
      #pragma unroll
      for (int c = 18; c < 32; c += 2) *(unsigned*)(Xb + tid*80 + c*2) = 0u;
      msh[tid] = mask[(size_t)g*128 + tid];
    }
    if (tid < 256) coords[tid] = xg[(tid >> 1)*18 + (tid & 1)];
    {
      const int which = tid >> 9, t = tid & 511;
      const uint4 v = *(const uint4*)(ws16 + 65536 + which*4096 + t*8);
      *(uint4*)(Wb + which*10240 + (t >> 2)*80 + (t & 3)*16) = v;
    }
  }
  __syncthreads();                                       // B0
  if (tid == 0){ float s = 0.f; for (int r = 0; r < 128; r++) s += msh[r]; *sN = s; }

  // ---- S3 (MFMA): f_het, gate; f_hetT -> Q, f_het row-major -> R (for S5 re-read)
  float gate[4][4];
  {
    f32x4 fhet[4]; f32x4 gf[4];
    ZACC(fhet); ZACC(gf);
    mmX(fhet, Xb, Wb, p, sub, l15, lhi);
    mmX(gf,   Xb, Wb + 10240, p, sub, l15, lhi);
    #pragma unroll
    for (int n0 = 0; n0 < 4; n0++){
      const float btv = b_t[(sub*4 + n0)*16 + l15];
      #pragma unroll
      for (int q = 0; q < 4; q++)
        gate[n0][q] = 1.f / (1.f + __expf(-(gf[n0][q] + btv)));
    }
    fragT_store(Qb, fhet, p, sub, l15, lhi);
    frag_store(Rb, fhet, p, sub, l15, lhi);   // fhet regs die here
  }

  // ---- S1: adj exact f32 -> adj_o + regs; deg -> nk ----
  float av[2][8];
  {
    float sc0[8], sc1[8], smv[8];
    #pragma unroll
    for (int j = 0; j < 8; j++){
      const int s = 8*ct + j;
      sc0[j] = coords[2*s]; sc1[j] = coords[2*s + 1]; smv[j] = msh[s];
    }
    #pragma unroll
    for (int i = 0; i < 2; i++){
      const int r = 2*rt2 + i;
      const float c0 = coords[2*r], c1 = coords[2*r + 1];
      const float mr = msh[r];
      float dsum = 0.f;
      #pragma unroll
      for (int j = 0; j < 8; j++){
        const float dx = c0 - sc0[j], dy = c1 - sc1[j];
        float dsq = dx*dx + dy*dy;
        dsq = fminf(fmaxf(dsq, 1e-12f), 1e12f);
        const float a = __expf(-__fsqrt_rn(dsq)) * (mr * smv[j]);
        av[i][j] = a; dsum += a;
      }
      #pragma unroll
      for (int o = 1; o < 16; o <<= 1) dsum += __shfl_xor(dsum, o);
      if (ct == 0){ const float t = dsum + 1e-6f; const float rs = __frsqrt_rn(t); nk[r] = rs*rs*rs; }
      *(float4*)(adj_o + (size_t)r*128 + 8*ct)     = make_float4(av[i][0],av[i][1],av[i][2],av[i][3]);
      *(float4*)(adj_o + (size_t)r*128 + 8*ct + 4) = make_float4(av[i][4],av[i][5],av[i][6],av[i][7]);
    }
  }
  __syncthreads();                                       // B1

  // ---- S2: A' = adj^3 * nk[r]*nk[s] -> P ----
  {
    float nkc[8];
    #pragma unroll
    for (int j = 0; j < 8; j++) nkc[j] = nk[8*ct + j];
    #pragma unroll
    for (int i = 0; i < 2; i++){
      const int r = 2*rt2 + i;
      const float nr = nk[r];
      float tv[8];
      #pragma unroll
      for (int j = 0; j < 8; j++){ const float a = av[i][j]; tv[j] = a*a*a*nr*nkc[j]; }
      *(uint4*)(Pb + SW(r, 16*ct)) = pk8(tv);
    }
  }
  __syncthreads();                                       // B2

  stageW(Wb, ws16, tid);                                 // wqkT (overlaps M2)

  // ---- M2: f_hom_pre = A' @ f_het ----
  f32x4 acc[4];
  ZACC(acc);
  mm_full(acc, Pb, Qb, p, sub, l15, lhi);
  __syncthreads();                                       // B4

  // ---- S5: og = gate*relu(f_hom)+(1-gate)*fhet(re-read from R) -> R + Q(ogT) ----
  {
    f32x4 ogv[4];
    #pragma unroll
    for (int n0 = 0; n0 < 4; n0++){
      const int col = (sub*4 + n0)*16 + l15;
      #pragma unroll
      for (int q = 0; q < 4; q++){
        const float fh = b2f(*(const unsigned short*)(Rb + SW(16*p + 4*lhi + q, 2*col)));
        const float gv = gate[n0][q];
        ogv[n0][q] = gv * fmaxf(acc[n0][q], 0.f) + (1.f - gv) * fh;
      }
    }
    frag_store(Rb, ogv, p, sub, l15, lhi);   // same addresses just read
    fragT_store(Qb, ogv, p, sub, l15, lhi);
  }
  __syncthreads();                                       // B5

  // ---- M3: t = og @ wqk -> P ----
  ZACC(acc);
  mm_full(acc, Rb, Wb, p, sub, l15, lhi);
  frag_store(Pb, acc, p, sub, l15, lhi);
  __syncthreads();                                       // B6

  stageW(Wb, ws16 + 16384, tid);                         // wvT (overlaps M4/M5)

  // ---- M4: logits; no-max masked softmax ----
  ZACC(acc);
  mm_full(acc, Pb, Rb, p, sub, l15, lhi);
  float ee[4][4];
  {
    float msv[4];
    #pragma unroll
    for (int n0 = 0; n0 < 4; n0++) msv[n0] = msh[(sub*4 + n0)*16 + l15];
    #pragma unroll
    for (int q = 0; q < 4; q++){
      const int row = 16*p + 4*lhi + q;
      float se = 0.f;
      #pragma unroll
      for (int n0 = 0; n0 < 4; n0++){
        const float e = __expf(acc[n0][q]) * msv[n0];
        ee[n0][q] = e; se += e;
      }
      #pragma unroll
      for (int o = 1; o < 16; o <<= 1) se += __shfl_xor(se, o);
      if (l15 == 0) csum[row*2 + sub] = se;
    }
  }
  __syncthreads();                                       // B7
  #pragma unroll
  for (int q = 0; q < 4; q++){
    const int row = 16*p + 4*lhi + q;
    const float inv = 1.f / (csum[row*2] + csum[row*2 + 1]);
    #pragma unroll
    for (int n0 = 0; n0 < 4; n0++){
      const float a = ee[n0][q] * inv;
      const int col = (sub*4 + n0)*16 + l15;
      att_o[(size_t)row*128 + col] = a;                  // f32 exact
      *(unsigned short*)(Pb + SW(row, 2*col)) = f2b(a);
    }
  }
  __syncthreads();                                       // B8

  uint4 w1r[2];
  loadW(w1r, ws16 + 32768, tid);                         // w1T -> regs (in flight)

  // ---- M5: u = attn @ og -> R ----
  ZACC(acc);
  mm_full(acc, Pb, Qb, p, sub, l15, lhi);
  frag_store(Rb, acc, p, sub, l15, lhi);
  __syncthreads();                                       // B9

  // ---- M6: sa = LN(u @ wv)*m -> Q + global ----
  ZACC(acc);
  mm_full(acc, Rb, Wb, p, sub, l15, lhi);
  {
    #pragma unroll
    for (int q = 0; q < 4; q++){
      const int row = 16*p + 4*lhi + q;
      float s1 = 0.f, s2 = 0.f;
      #pragma unroll
      for (int n0 = 0; n0 < 4; n0++){ const float v = acc[n0][q]; s1 += v; s2 += v*v; }
      #pragma unroll
      for (int o = 1; o < 16; o <<= 1){ s1 += __shfl_xor(s1, o); s2 += __shfl_xor(s2, o); }
      if (l15 == 0){ csum[row*4 + sub*2] = s1; csum[row*4 + sub*2 + 1] = s2; }
    }
  }
  __syncthreads();                                       // B10
  {
    f32x4 sav[4];
    float gsa[4], bsa[4];
    #pragma unroll
    for (int n0 = 0; n0 < 4; n0++){ const int c = (sub*4+n0)*16 + l15; gsa[n0] = g_sa[c]; bsa[n0] = be_sa[c]; }
    #pragma unroll
    for (int q = 0; q < 4; q++){
      const int row = 16*p + 4*lhi + q;
      const float s1 = csum[row*4] + csum[row*4 + 2];
      const float s2 = csum[row*4 + 1] + csum[row*4 + 3];
      const float mean = s1 * 0.0078125f;
      const float var  = s2 * 0.0078125f - mean*mean;
      const float rstd = __frsqrt_rn(var + 1e-3f);
      const float mr = msh[row];
      #pragma unroll
      for (int n0 = 0; n0 < 4; n0++){
        const float y = ((acc[n0][q] - mean) * rstd * gsa[n0] + bsa[n0]) * mr;
        sav[n0][q] = y;
        sa_o[(size_t)row*128 + (sub*4+n0)*16 + l15] = y;  // f32 exact
      }
    }
    frag_store(Qb, sav, p, sub, l15, lhi);   // sav regs die here; M8 re-reads Q
  }
  __syncthreads();                                       // B11
  writeW(Wb, w1r, tid);                                  // w1T -> LDS
  __syncthreads();                                       // B12

  // ---- M7: d1 = relu(sa @ w1 + b1) -> P ----
  ZACC(acc);
  mm_full(acc, Qb, Wb, p, sub, l15, lhi);
  {
    f32x4 d1v[4];
    #pragma unroll
    for (int n0 = 0; n0 < 4; n0++){
      const float b1v = b1[(sub*4 + n0)*16 + l15];
      #pragma unroll
      for (int q = 0; q < 4; q++) d1v[n0][q] = fmaxf(acc[n0][q] + b1v, 0.f);
    }
    frag_store(Pb, d1v, p, sub, l15, lhi);
  }
  uint4 w2r[2];
  loadW(w2r, ws16 + 49152, tid);                         // w2T -> regs
  __syncthreads();                                       // B13
  writeW(Wb, w2r, tid);
  __syncthreads();                                       // B14

  // ---- M8: d2=relu(d1@w2+b2); dense=LN(d2 + sa(from Q))*m -> global; pool ----
  ZACC(acc);
  mm_full(acc, Pb, Wb, p, sub, l15, lhi);
  {
    float b2v[4], gov[4], bov[4], dd[4][4];
    #pragma unroll
    for (int n0 = 0; n0 < 4; n0++){
      const int c = (sub*4 + n0)*16 + l15;
      b2v[n0] = b2[c]; gov[n0] = g_out[c]; bov[n0] = be_out[c];
    }
    #pragma unroll
    for (int q = 0; q < 4; q++){
      const int row = 16*p + 4*lhi + q;
      float s1 = 0.f, s2 = 0.f;
      #pragma unroll
      for (int n0 = 0; n0 < 4; n0++){
        const int col = (sub*4 + n0)*16 + l15;
        const float sv = b2f(*(const unsigned short*)(Qb + SW(row, 2*col)));
        const float v = fmaxf(acc[n0][q] + b2v[n0], 0.f) + sv;
        dd[n0][q] = v; s1 += v; s2 += v*v;
      }
      #pragma unroll
      for (int o = 1; o < 16; o <<= 1){ s1 += __shfl_xor(s1, o); s2 += __shfl_xor(s2, o); }
      if (l15 == 0){ csum[row*4 + sub*2] = s1; csum[row*4 + sub*2 + 1] = s2; }
    }
    __syncthreads();                                     // B15
    float cs[4] = {0.f, 0.f, 0.f, 0.f};
    #pragma unroll
    for (int q = 0; q < 4; q++){
      const int row = 16*p + 4*lhi + q;
      const float s1 = csum[row*4] + csum[row*4 + 2];
      const float s2 = csum[row*4 + 1] + csum[row*4 + 3];
      const float mean = s1 * 0.0078125f;
      const float var  = s2 * 0.0078125f - mean*mean;
      const float rstd = __frsqrt_rn(var + 1e-3f);
      const float mr = msh[row];
      #pragma unroll
      for (int n0 = 0; n0 < 4; n0++){
        const float y = ((dd[n0][q] - mean) * rstd * gov[n0] + bov[n0]) * mr;
        den_o[(size_t)row*128 + (sub*4+n0)*16 + l15] = y;  // f32 exact
        cs[n0] += y;
      }
    }
    #pragma unroll
    for (int n0 = 0; n0 < 4; n0++){
      float v = cs[n0];
      v += __shfl_xor(v, 16); v += __shfl_xor(v, 32);
      if (lhi == 0) pool[p*128 + (sub*4 + n0)*16 + l15] = v;
    }
  }
  __syncthreads();                                       // B16
  if (tid < 128){
    float s = 0.f;
    #pragma unroll
    for (int q = 0; q < 8; q++) s += pool[q*128 + tid];
    const float n = *sN;
    out0[(size_t)g*128 + tid] = (n > 0.f) ? (s / n) : 0.f;
  }
}

extern "C" void kernel_launch(void* const* d_in, const int* in_sizes, int n_in,
                              void* d_out, int out_size, void* d_ws, size_t ws_size,
                              hipStream_t stream) {
  (void)in_sizes; (void)n_in; (void)out_size; (void)ws_size;
  const float* x     = (const float*)d_in[0];
  const float* mask  = (const float*)d_in[1];
  const float* theta = (const float*)d_in[2];
  const float* w_t   = (const float*)d_in[3];
  const float* b_t   = (const float*)d_in[4];
  const float* wq    = (const float*)d_in[5];
  const float* wk    = (const float*)d_in[6];
  const float* wvp   = (const float*)d_in[7];
  const float* w1    = (const float*)d_in[8];
  const float* b1    = (const float*)d_in[9];
  const float* w2    = (const float*)d_in[10];
  const float* b2    = (const float*)d_in[11];
  const float* g_sa  = (const float*)d_in[12];
  const float* be_sa = (const float*)d_in[13];
  const float* g_out = (const float*)d_in[14];
  const float* be_out= (const float*)d_in[15];
  unsigned short* ws16 = (unsigned short*)d_ws;

  prep_wqkT<<<dim3(128), dim3(128), 0, stream>>>(wq, wk, ws16);
  prep_T<<<dim3(224), dim3(256), 0, stream>>>(wvp, w1, w2, theta, w_t, ws16);

  (void)hipFuncSetAttribute(reinterpret_cast<const void*>(fused_gcn),
                            hipFuncAttributeMaxDynamicSharedMemorySize, SMEM_SZ);
  fused_gcn<<<dim3(Gg), dim3(NT), SMEM_SZ, stream>>>(
      x, mask, b_t, ws16, b1, b2, g_sa, be_sa, g_out, be_out, (float*)d_out);
}

// Round 12
// 152.517 us; speedup vs baseline: 1.2922x; 1.1807x over previous
//
#include <hip/hip_runtime.h>
#include <math.h>

// RechitsGCN fused — round 12: R9 (159 µs best) + VALU-chain trims only.
// (no clamps in S1; v_rcp for sigmoid/softmax/pool divides; parallel sN;
//  mul-shift /18). Traffic counters proven non-binding (R3-R11: 14x traffic
//  swing, ±12% dur) — remaining cost is the serial 15-phase barrier chain.
#define Gg 1024
#define NT 1024

typedef __bf16 bf16x8 __attribute__((ext_vector_type(8)));
typedef float  f32x4  __attribute__((ext_vector_type(4)));

#define P_OFF   0
#define Q_OFF   32768
#define R_OFF   65536
#define W_OFF   98304
#define XB_OFF  131072
#define CO_OFF  141312
#define MS_OFF  142336
#define NK_OFF  142848
#define CS_OFF  143360
#define PL_OFF  145408
#define SN_OFF  149504
#define SMEM_SZ 149520

__device__ __forceinline__ unsigned short f2b(float f){
  return __builtin_bit_cast(unsigned short, (__bf16)f);
}
__device__ __forceinline__ float b2f(unsigned short h){
  return __uint_as_float(((unsigned)h) << 16);
}
__device__ __forceinline__ float frcp(float x){ return __builtin_amdgcn_rcpf(x); }
__device__ __forceinline__ int SW(int row, int bc){ return (row << 8) + (bc ^ ((row & 7) << 4)); }

__device__ __forceinline__ uint4 pk8(const float* f){
  uint4 v;
  v.x = (unsigned)f2b(f[0]) | ((unsigned)f2b(f[1])<<16);
  v.y = (unsigned)f2b(f[2]) | ((unsigned)f2b(f[3])<<16);
  v.z = (unsigned)f2b(f[4]) | ((unsigned)f2b(f[5])<<16);
  v.w = (unsigned)f2b(f[6]) | ((unsigned)f2b(f[7])<<16);
  return v;
}
__device__ __forceinline__ f32x4 MFMA(uint4 a, uint4 b, f32x4 c){
  return __builtin_amdgcn_mfma_f32_16x16x32_bf16(
      __builtin_bit_cast(bf16x8, a), __builtin_bit_cast(bf16x8, b), c, 0, 0, 0);
}
#define ZACC(A) { f32x4 z_={0.f,0.f,0.f,0.f}; A[0]=z_; A[1]=z_; A[2]=z_; A[3]=z_; }

__device__ __forceinline__ void mm_full(f32x4* acc, const char* A, const char* B,
                                        int p, int sub, int l15, int lhi){
  #pragma unroll
  for (int ks = 0; ks < 4; ks++){
    const int kb = ks*64 + lhi*16;
    const uint4 a = *(const uint4*)(A + SW(16*p + l15, kb));
    #pragma unroll
    for (int n0 = 0; n0 < 4; n0++){
      const uint4 b = *(const uint4*)(B + SW((sub*4 + n0)*16 + l15, kb));
      acc[n0] = MFMA(a, b, acc[n0]);
    }
  }
}
__device__ __forceinline__ void mmX(f32x4* acc, const char* Xb, const char* Wt,
                                    int p, int sub, int l15, int lhi){
  const uint4 a = *(const uint4*)(Xb + 80*(16*p + l15) + lhi*16);
  #pragma unroll
  for (int n0 = 0; n0 < 4; n0++){
    const uint4 b = *(const uint4*)(Wt + 80*((sub*4 + n0)*16 + l15) + lhi*16);
    acc[n0] = MFMA(a, b, acc[n0]);
  }
}
__device__ __forceinline__ void frag_store(char* buf, const f32x4* acc,
                                           int p, int sub, int l15, int lhi){
  #pragma unroll
  for (int n0 = 0; n0 < 4; n0++){
    const int col = (sub*4 + n0)*16 + l15;
    #pragma unroll
    for (int q = 0; q < 4; q++)
      *(unsigned short*)(buf + SW(16*p + 4*lhi + q, 2*col)) = f2b(acc[n0][q]);
  }
}
__device__ __forceinline__ void fragT_store(char* buf, const f32x4* acc,
                                            int p, int sub, int l15, int lhi){
  const int row0 = 16*p + 4*lhi;
  #pragma unroll
  for (int n0 = 0; n0 < 4; n0++){
    const int col = (sub*4 + n0)*16 + l15;
    uint2 u;
    u.x = (unsigned)f2b(acc[n0][0]) | ((unsigned)f2b(acc[n0][1])<<16);
    u.y = (unsigned)f2b(acc[n0][2]) | ((unsigned)f2b(acc[n0][3])<<16);
    *(uint2*)(buf + SW(col, 2*row0)) = u;
  }
}
__device__ __forceinline__ void stageW(char* W, const unsigned short* src, int tid){
  #pragma unroll
  for (int q = 0; q < 2; q++){
    const int chunk = q*NT + tid;
    const uint4 v = *(const uint4*)(src + chunk*8);
    *(uint4*)(W + SW(chunk >> 4, (chunk & 15)*16)) = v;
  }
}
__device__ __forceinline__ void loadW(uint4* r, const unsigned short* src, int tid){
  r[0] = *(const uint4*)(src + (size_t)tid*8);
  r[1] = *(const uint4*)(src + (size_t)(NT + tid)*8);
}
__device__ __forceinline__ void writeW(char* W, const uint4* r, int tid){
  *(uint4*)(W + SW(tid >> 4, (tid & 15)*16)) = r[0];
  *(uint4*)(W + SW((NT + tid) >> 4, ((NT + tid) & 15)*16)) = r[1];
}

__global__ __launch_bounds__(128) void prep_wqkT(const float* __restrict__ wq,
                                                 const float* __restrict__ wk,
                                                 unsigned short* __restrict__ ws16){
  __shared__ unsigned short wqb[128*130];
  __shared__ float wkr[128];
  const int h = blockIdx.x, t = threadIdx.x;
  for (int i = t; i < 16384; i += 128){ int a = i >> 7, c = i & 127; wqb[a*130+c] = f2b(wq[i]); }
  wkr[t] = wk[h*128 + t];
  __syncthreads();
  float s = 0.f;
  for (int c = 0; c < 128; c++) s += b2f(wqb[t*130 + c]) * wkr[c];
  ws16[h*128 + t] = f2b(s * 0.08838834764831845f);
}

__global__ __launch_bounds__(256) void prep_T(const float* __restrict__ wv,
                                              const float* __restrict__ w1,
                                              const float* __restrict__ w2,
                                              const float* __restrict__ theta,
                                              const float* __restrict__ w_t,
                                              unsigned short* __restrict__ ws16){
  const int i = blockIdx.x*256 + threadIdx.x;
  if (i < 49152){
    const int which = i >> 14, r = i & 16383;
    const int hh = r >> 7, aa = r & 127;
    const float* s = (which == 0) ? wv : (which == 1) ? w1 : w2;
    ws16[16384 + i] = f2b(s[aa*128 + hh]);
  } else if (i < 57344){
    const int t2 = i - 49152;
    const int mat = t2 >> 12, r = t2 & 4095;
    const int hh = r >> 5, kk = r & 31;
    const float* s = (mat == 0) ? theta : w_t;
    ws16[16384 + i] = (kk < 18) ? f2b(s[kk*128 + hh]) : (unsigned short)0;
  }
}

__global__ void __launch_bounds__(NT)
__attribute__((amdgpu_waves_per_eu(4, 4)))
fused_gcn(const float* __restrict__ x, const float* __restrict__ mask,
          const float* __restrict__ b_t, const unsigned short* __restrict__ ws16,
          const float* __restrict__ b1, const float* __restrict__ b2,
          const float* __restrict__ g_sa, const float* __restrict__ be_sa,
          const float* __restrict__ g_out, const float* __restrict__ be_out,
          float* __restrict__ out)
{
  extern __shared__ char smc[];
  char* Pb = smc + P_OFF;
  char* Qb = smc + Q_OFF;
  char* Rb = smc + R_OFF;
  char* Wb = smc + W_OFF;
  char* Xb = smc + XB_OFF;
  float* coords = (float*)(smc + CO_OFF);
  float* msh    = (float*)(smc + MS_OFF);
  float* nk     = (float*)(smc + NK_OFF);
  float* csum   = (float*)(smc + CS_OFF);
  float* pool   = (float*)(smc + PL_OFF);
  float* sN     = (float*)(smc + SN_OFF);

  const int g    = blockIdx.x;
  const int tid  = threadIdx.x;
  const int lane = tid & 63;
  const int wv_  = tid >> 6;
  const int p    = wv_ >> 1;
  const int sub  = wv_ & 1;
  const int l15  = lane & 15;
  const int lhi  = lane >> 4;
  const int rt2  = tid >> 4;
  const int ct   = tid & 15;

  const size_t gRH = (size_t)g * 16384;
  float* out0  = out;
  float* sa_o  = out + (size_t)Gg*128 + gRH;
  float* den_o = out + (size_t)Gg*128 + (size_t)Gg*16384 + gRH;
  float* att_o = out + (size_t)Gg*128 + 2*(size_t)Gg*16384 + gRH;
  float* adj_o = out + (size_t)Gg*128 + 3*(size_t)Gg*16384 + gRH;

  // ---- S0: stage x->Xb bf16, coords, mask, thetaT/w_tT->W ----
  {
    const float* xg = x + (size_t)g * 2304;
    for (int i = tid; i < 2304; i += NT){
      const int r = (int)(((unsigned)i * 3641u) >> 16);   // i/18 exact for i<2304
      const int k = i - r*18;
      *(unsigned short*)(Xb + r*80 + k*2) = f2b(xg[i]);
    }
    if (tid < 128){
      #pragma unroll
      for (int c = 18; c < 32; c += 2) *(unsigned*)(Xb + tid*80 + c*2) = 0u;
      msh[tid] = mask[(size_t)g*128 + tid];
    }
    if (tid < 256) coords[tid] = xg[(tid >> 1)*18 + (tid & 1)];
    {
      const int which = tid >> 9, t = tid & 511;
      const uint4 v = *(const uint4*)(ws16 + 65536 + which*4096 + t*8);
      *(uint4*)(Wb + which*10240 + (t >> 2)*80 + (t & 3)*16) = v;
    }
  }
  __syncthreads();                                       // B0
  if (tid < 64){                                         // parallel sN (wave 0)
    float v = msh[tid] + msh[tid + 64];
    #pragma unroll
    for (int o = 1; o < 64; o <<= 1) v += __shfl_xor(v, o);
    if (tid == 0) *sN = v;
  }

  // ---- S3 (MFMA): f_het, gate; f_hetT -> Q ----
  f32x4 fhet[4]; float gate[4][4];
  {
    f32x4 gf[4];
    ZACC(fhet); ZACC(gf);
    mmX(fhet, Xb, Wb, p, sub, l15, lhi);
    mmX(gf,   Xb, Wb + 10240, p, sub, l15, lhi);
    #pragma unroll
    for (int n0 = 0; n0 < 4; n0++){
      const float btv = b_t[(sub*4 + n0)*16 + l15];
      #pragma unroll
      for (int q = 0; q < 4; q++)
        gate[n0][q] = frcp(1.f + __expf(-(gf[n0][q] + btv)));
    }
    fragT_store(Qb, fhet, p, sub, l15, lhi);
  }

  // ---- S1: adj exact f32 (no clamps needed: dsq in (0,1e12)) -> adj_o + regs; nk ----
  float av[2][8];
  {
    float sc0[8], sc1[8], smv[8];
    #pragma unroll
    for (int j = 0; j < 8; j++){
      const int s = 8*ct + j;
      sc0[j] = coords[2*s]; sc1[j] = coords[2*s + 1]; smv[j] = msh[s];
    }
    #pragma unroll
    for (int i = 0; i < 2; i++){
      const int r = 2*rt2 + i;
      const float c0 = coords[2*r], c1 = coords[2*r + 1];
      const float mr = msh[r];
      float dsum = 0.f;
      #pragma unroll
      for (int j = 0; j < 8; j++){
        const float dx = c0 - sc0[j], dy = c1 - sc1[j];
        float dsq = dx*dx + dy*dy;
        dsq = fmaxf(dsq, 1e-12f);                        // keep floor only (exact-zero diag)
        const float a = __expf(-__fsqrt_rn(dsq)) * (mr * smv[j]);
        av[i][j] = a; dsum += a;
      }
      #pragma unroll
      for (int o = 1; o < 16; o <<= 1) dsum += __shfl_xor(dsum, o);
      if (ct == 0){ const float t = dsum + 1e-6f; const float rs = __frsqrt_rn(t); nk[r] = rs*rs*rs; }
      *(float4*)(adj_o + (size_t)r*128 + 8*ct)     = make_float4(av[i][0],av[i][1],av[i][2],av[i][3]);
      *(float4*)(adj_o + (size_t)r*128 + 8*ct + 4) = make_float4(av[i][4],av[i][5],av[i][6],av[i][7]);
    }
  }
  __syncthreads();                                       // B1

  // ---- S2: A' = adj^3 * nk[r]*nk[s] -> P ----
  {
    float nkc[8];
    #pragma unroll
    for (int j = 0; j < 8; j++) nkc[j] = nk[8*ct + j];
    #pragma unroll
    for (int i = 0; i < 2; i++){
      const int r = 2*rt2 + i;
      const float nr = nk[r];
      float tv[8];
      #pragma unroll
      for (int j = 0; j < 8; j++){ const float a = av[i][j]; tv[j] = a*a*a*nr*nkc[j]; }
      *(uint4*)(Pb + SW(r, 16*ct)) = pk8(tv);
    }
  }
  __syncthreads();                                       // B2

  stageW(Wb, ws16, tid);                                 // wqkT (overlaps M2)

  // ---- M2: f_hom_pre = A' @ f_het ----
  f32x4 acc[4];
  ZACC(acc);
  mm_full(acc, Pb, Qb, p, sub, l15, lhi);
  __syncthreads();                                       // B4

  // ---- S5: og -> R + ogT -> Q ----
  {
    f32x4 ogv[4];
    #pragma unroll
    for (int n0 = 0; n0 < 4; n0++)
      #pragma unroll
      for (int q = 0; q < 4; q++){
        const float gv = gate[n0][q];
        ogv[n0][q] = gv * fmaxf(acc[n0][q], 0.f) + (1.f - gv) * fhet[n0][q];
      }
    frag_store(Rb, ogv, p, sub, l15, lhi);
    fragT_store(Qb, ogv, p, sub, l15, lhi);
  }
  __syncthreads();                                       // B5

  // ---- M3: t = og @ wqk -> P ----
  ZACC(acc);
  mm_full(acc, Rb, Wb, p, sub, l15, lhi);
  frag_store(Pb, acc, p, sub, l15, lhi);
  __syncthreads();                                       // B6

  stageW(Wb, ws16 + 16384, tid);                         // wvT (overlaps M4/M5)

  // ---- M4: logits; no-max masked softmax ----
  ZACC(acc);
  mm_full(acc, Pb, Rb, p, sub, l15, lhi);
  float ee[4][4];
  {
    float msv[4];
    #pragma unroll
    for (int n0 = 0; n0 < 4; n0++) msv[n0] = msh[(sub*4 + n0)*16 + l15];
    #pragma unroll
    for (int q = 0; q < 4; q++){
      const int row = 16*p + 4*lhi + q;
      float se = 0.f;
      #pragma unroll
      for (int n0 = 0; n0 < 4; n0++){
        const float e = __expf(acc[n0][q]) * msv[n0];
        ee[n0][q] = e; se += e;
      }
      #pragma unroll
      for (int o = 1; o < 16; o <<= 1) se += __shfl_xor(se, o);
      if (l15 == 0) csum[row*2 + sub] = se;
    }
  }
  __syncthreads();                                       // B7
  #pragma unroll
  for (int q = 0; q < 4; q++){
    const int row = 16*p + 4*lhi + q;
    const float inv = frcp(csum[row*2] + csum[row*2 + 1]);
    #pragma unroll
    for (int n0 = 0; n0 < 4; n0++){
      const float a = ee[n0][q] * inv;
      const int col = (sub*4 + n0)*16 + l15;
      att_o[(size_t)row*128 + col] = a;                  // f32
      *(unsigned short*)(Pb + SW(row, 2*col)) = f2b(a);
    }
  }
  __syncthreads();                                       // B8

  uint4 w1r[2];
  loadW(w1r, ws16 + 32768, tid);                         // w1T -> regs (in flight)

  // ---- M5: u = attn @ og -> R ----
  ZACC(acc);
  mm_full(acc, Pb, Qb, p, sub, l15, lhi);
  frag_store(Rb, acc, p, sub, l15, lhi);
  __syncthreads();                                       // B9

  // ---- M6: sa = LN(u @ wv)*m -> Q + global + regs ----
  ZACC(acc);
  mm_full(acc, Rb, Wb, p, sub, l15, lhi);
  f32x4 sav[4];
  {
    #pragma unroll
    for (int q = 0; q < 4; q++){
      const int row = 16*p + 4*lhi + q;
      float s1 = 0.f, s2 = 0.f;
      #pragma unroll
      for (int n0 = 0; n0 < 4; n0++){ const float v = acc[n0][q]; s1 += v; s2 += v*v; }
      #pragma unroll
      for (int o = 1; o < 16; o <<= 1){ s1 += __shfl_xor(s1, o); s2 += __shfl_xor(s2, o); }
      if (l15 == 0){ csum[row*4 + sub*2] = s1; csum[row*4 + sub*2 + 1] = s2; }
    }
  }
  __syncthreads();                                       // B10
  {
    float gsa[4], bsa[4];
    #pragma unroll
    for (int n0 = 0; n0 < 4; n0++){ const int c = (sub*4+n0)*16 + l15; gsa[n0] = g_sa[c]; bsa[n0] = be_sa[c]; }
    #pragma unroll
    for (int q = 0; q < 4; q++){
      const int row = 16*p + 4*lhi + q;
      const float s1 = csum[row*4] + csum[row*4 + 2];
      const float s2 = csum[row*4 + 1] + csum[row*4 + 3];
      const float mean = s1 * 0.0078125f;
      const float var  = s2 * 0.0078125f - mean*mean;
      const float rstd = __frsqrt_rn(var + 1e-3f);
      const float mr = msh[row];
      #pragma unroll
      for (int n0 = 0; n0 < 4; n0++){
        const float y = ((acc[n0][q] - mean) * rstd * gsa[n0] + bsa[n0]) * mr;
        sav[n0][q] = y;
        sa_o[(size_t)row*128 + (sub*4+n0)*16 + l15] = y;  // f32
      }
    }
    frag_store(Qb, sav, p, sub, l15, lhi);
  }
  __syncthreads();                                       // B11
  writeW(Wb, w1r, tid);                                  // w1T -> LDS
  __syncthreads();                                       // B12

  // ---- M7: d1 = relu(sa @ w1 + b1) -> P ----
  ZACC(acc);
  mm_full(acc, Qb, Wb, p, sub, l15, lhi);
  {
    f32x4 d1v[4];
    #pragma unroll
    for (int n0 = 0; n0 < 4; n0++){
      const float b1v = b1[(sub*4 + n0)*16 + l15];
      #pragma unroll
      for (int q = 0; q < 4; q++) d1v[n0][q] = fmaxf(acc[n0][q] + b1v, 0.f);
    }
    frag_store(Pb, d1v, p, sub, l15, lhi);
  }
  uint4 w2r[2];
  loadW(w2r, ws16 + 49152, tid);                         // w2T -> regs
  __syncthreads();                                       // B13
  writeW(Wb, w2r, tid);
  __syncthreads();                                       // B14

  // ---- M8: d2=relu(d1@w2+b2); dense=LN(d2+sa)*m -> global; pool ----
  ZACC(acc);
  mm_full(acc, Pb, Wb, p, sub, l15, lhi);
  {
    float b2v[4], gov[4], bov[4], dd[4][4];
    #pragma unroll
    for (int n0 = 0; n0 < 4; n0++){
      const int c = (sub*4 + n0)*16 + l15;
      b2v[n0] = b2[c]; gov[n0] = g_out[c]; bov[n0] = be_out[c];
    }
    #pragma unroll
    for (int q = 0; q < 4; q++){
      const int row = 16*p + 4*lhi + q;
      float s1 = 0.f, s2 = 0.f;
      #pragma unroll
      for (int n0 = 0; n0 < 4; n0++){
        const float v = fmaxf(acc[n0][q] + b2v[n0], 0.f) + sav[n0][q];
        dd[n0][q] = v; s1 += v; s2 += v*v;
      }
      #pragma unroll
      for (int o = 1; o < 16; o <<= 1){ s1 += __shfl_xor(s1, o); s2 += __shfl_xor(s2, o); }
      if (l15 == 0){ csum[row*4 + sub*2] = s1; csum[row*4 + sub*2 + 1] = s2; }
    }
    __syncthreads();                                     // B15
    float cs[4] = {0.f, 0.f, 0.f, 0.f};
    #pragma unroll
    for (int q = 0; q < 4; q++){
      const int row = 16*p + 4*lhi + q;
      const float s1 = csum[row*4] + csum[row*4 + 2];
      const float s2 = csum[row*4 + 1] + csum[row*4 + 3];
      const float mean = s1 * 0.0078125f;
      const float var  = s2 * 0.0078125f - mean*mean;
      const float rstd = __frsqrt_rn(var + 1e-3f);
      const float mr = msh[row];
      #pragma unroll
      for (int n0 = 0; n0 < 4; n0++){
        const float y = ((dd[n0][q] - mean) * rstd * gov[n0] + bov[n0]) * mr;
        den_o[(size_t)row*128 + (sub*4+n0)*16 + l15] = y;  // f32
        cs[n0] += y;
      }
    }
    #pragma unroll
    for (int n0 = 0; n0 < 4; n0++){
      float v = cs[n0];
      v += __shfl_xor(v, 16); v += __shfl_xor(v, 32);
      if (lhi == 0) pool[p*128 + (sub*4 + n0)*16 + l15] = v;
    }
  }
  __syncthreads();                                       // B16
  if (tid < 128){
    float s = 0.f;
    #pragma unroll
    for (int q = 0; q < 8; q++) s += pool[q*128 + tid];
    const float n = *sN;
    out0[(size_t)g*128 + tid] = (n > 0.f) ? (s * frcp(n)) : 0.f;
  }
}

extern "C" void kernel_launch(void* const* d_in, const int* in_sizes, int n_in,
                              void* d_out, int out_size, void* d_ws, size_t ws_size,
                              hipStream_t stream) {
  (void)in_sizes; (void)n_in; (void)out_size; (void)ws_size;
  const float* x     = (const float*)d_in[0];
  const float* mask  = (const float*)d_in[1];
  const float* theta = (const float*)d_in[2];
  const float* w_t   = (const float*)d_in[3];
  const float* b_t   = (const float*)d_in[4];
  const float* wq    = (const float*)d_in[5];
  const float* wk    = (const float*)d_in[6];
  const float* wvp   = (const float*)d_in[7];
  const float* w1    = (const float*)d_in[8];
  const float* b1    = (const float*)d_in[9];
  const float* w2    = (const float*)d_in[10];
  const float* b2    = (const float*)d_in[11];
  const float* g_sa  = (const float*)d_in[12];
  const float* be_sa = (const float*)d_in[13];
  const float* g_out = (const float*)d_in[14];
  const float* be_out= (const float*)d_in[15];
  unsigned short* ws16 = (unsigned short*)d_ws;

  prep_wqkT<<<dim3(128), dim3(128), 0, stream>>>(wq, wk, ws16);
  prep_T<<<dim3(224), dim3(256), 0, stream>>>(wvp, w1, w2, theta, w_t, ws16);

  (void)hipFuncSetAttribute(reinterpret_cast<const void*>(fused_gcn),
                            hipFuncAttributeMaxDynamicSharedMemorySize, SMEM_SZ);
  fused_gcn<<<dim3(Gg), dim3(NT), SMEM_SZ, stream>>>(
      x, mask, b_t, ws16, b1, b2, g_sa, be_sa, g_out, be_out, (float*)d_out);
}